// Round 13
// baseline (312.727 us; speedup 1.0000x reference)
//
#include <hip/hip_runtime.h>
#include <hip/hip_bf16.h>

#define NN 8192
#define NFEAT 512
#define NHID 64
#define NCLASS 16
#define NHEAD 4
#define ALPHA 0.1f
#define CAP 768

typedef short bf16x8 __attribute__((ext_vector_type(8)));
typedef float f32x4 __attribute__((ext_vector_type(4)));
typedef float fv4 __attribute__((ext_vector_type(4)));

__device__ __forceinline__ float lrelu(float x) { return fmaxf(x, ALPHA * x); }
__device__ __forceinline__ float elu(float x) { return x > 0.f ? x : __expf(x) - 1.f; }
__device__ __forceinline__ short f2b(float x) {
  union { __bf16 b; short s; } c; c.b = (__bf16)x; return c.s;
}
__device__ __forceinline__ float b2f(short x) {
  union { unsigned int u; float f; } c; c.u = ((unsigned int)(unsigned short)x) << 16; return c.f;
}

#define UPF(w, v, A0, A1)                                  \
  {                                                        \
    const float lo_ = __uint_as_float((v) << 16);          \
    const float hi_ = __uint_as_float((v) & 0xffff0000u);  \
    (A0) += (w) * lo_;                                     \
    (A1) += (w) * hi_;                                     \
  }

// ---------------- K0b: WB[h][d][k] = bf16(W[h][k][d]) ----------------
__global__ __launch_bounds__(256) void k_wprep(const float* __restrict__ W,
                                               short* __restrict__ WB) {
  __shared__ float t[64][65];
  const int h = blockIdx.y;
  const int k0 = blockIdx.x * 64;
  const int tid = threadIdx.x;
#pragma unroll
  for (int it = 0; it < 16; ++it) {
    const int r = it * 4 + (tid >> 6), c = tid & 63;
    t[r][c] = W[((size_t)h * NFEAT + k0 + r) * NHID + c];
  }
  __syncthreads();
#pragma unroll
  for (int it = 0; it < 16; ++it) {
    const int d = it * 4 + (tid >> 6), k = tid & 63;
    WB[((size_t)h * NHID + d) * NFEAT + k0 + k] = f2b(t[k][d]);
  }
}

// ---------------- K1: Wh = bf16(x) @ WB^T (MFMA); epilogue f1/f2 + Whf j-blocked ------
__global__ __launch_bounds__(256) void k_prep1(const float* __restrict__ x,
                                               const short* __restrict__ WB,
                                               const float* __restrict__ a,
                                               short* __restrict__ Whf,
                                               float* __restrict__ f1i,
                                               float* __restrict__ f2i) {
  __shared__ short tile[64][72];
  const int bid = blockIdx.x;
  const int h = bid >> 7;
  const int bm = (bid & 127) * 64;
  const int tid = threadIdx.x;
  const int wv = tid >> 6, lane = tid & 63;
  const int mr = lane & 15, kg = lane >> 4;
  f32x4 acc0 = {0.f, 0.f, 0.f, 0.f}, acc1 = acc0, acc2 = acc0, acc3 = acc0;
  const float* ap = x + (size_t)(bm + wv * 16 + mr) * NFEAT + kg * 8;
  const short* bp = WB + ((size_t)h * NHID + mr) * NFEAT + kg * 8;
#pragma unroll 2
  for (int k0 = 0; k0 < NFEAT; k0 += 32) {
    const float4 xa = *reinterpret_cast<const float4*>(ap);
    const float4 xb = *reinterpret_cast<const float4*>(ap + 4);
    bf16x8 af;
    af[0] = f2b(xa.x); af[1] = f2b(xa.y); af[2] = f2b(xa.z); af[3] = f2b(xa.w);
    af[4] = f2b(xb.x); af[5] = f2b(xb.y); af[6] = f2b(xb.z); af[7] = f2b(xb.w);
    const bf16x8 b0 = *reinterpret_cast<const bf16x8*>(bp);
    const bf16x8 b1 = *reinterpret_cast<const bf16x8*>(bp + 16 * NFEAT);
    const bf16x8 b2 = *reinterpret_cast<const bf16x8*>(bp + 32 * NFEAT);
    const bf16x8 b3 = *reinterpret_cast<const bf16x8*>(bp + 48 * NFEAT);
    acc0 = __builtin_amdgcn_mfma_f32_16x16x32_bf16(af, b0, acc0, 0, 0, 0);
    acc1 = __builtin_amdgcn_mfma_f32_16x16x32_bf16(af, b1, acc1, 0, 0, 0);
    acc2 = __builtin_amdgcn_mfma_f32_16x16x32_bf16(af, b2, acc2, 0, 0, 0);
    acc3 = __builtin_amdgcn_mfma_f32_16x16x32_bf16(af, b3, acc3, 0, 0, 0);
    ap += 32; bp += 32;
  }
  float a1v[4], a2v[4];
#pragma unroll
  for (int c = 0; c < 4; ++c) {
    a1v[c] = a[h * 128 + mr + c * 16];
    a2v[c] = a[h * 128 + 64 + mr + c * 16];
  }
#pragma unroll
  for (int q = 0; q < 4; ++q) {
    float s1 = acc0[q] * a1v[0] + acc1[q] * a1v[1] + acc2[q] * a1v[2] + acc3[q] * a1v[3];
    float s2 = acc0[q] * a2v[0] + acc1[q] * a2v[1] + acc2[q] * a2v[2] + acc3[q] * a2v[3];
#pragma unroll
    for (int off = 1; off < 16; off <<= 1) {
      s1 += __shfl_xor(s1, off);
      s2 += __shfl_xor(s2, off);
    }
    if (mr == 0) {
      const int i = bm + wv * 16 + kg * 4 + q;
      f1i[(size_t)i * 4 + h] = s1;
      f2i[(size_t)i * 4 + h] = s2;
    }
  }
#pragma unroll
  for (int q = 0; q < 4; ++q) {
    const int r = wv * 16 + kg * 4 + q;
    tile[r][mr +  0] = f2b(acc0[q]);
    tile[r][mr + 16] = f2b(acc1[q]);
    tile[r][mr + 32] = f2b(acc2[q]);
    tile[r][mr + 48] = f2b(acc3[q]);
  }
  __syncthreads();
#pragma unroll
  for (int it = 0; it < 2; ++it) {
    const int jbl = (tid >> 6) + it * 4;
    const int d = tid & 63;
    bf16x8 o;
#pragma unroll
    for (int jo = 0; jo < 8; ++jo) o[jo] = tile[jbl * 8 + jo][d];
    *reinterpret_cast<bf16x8*>(Whf +
        (((size_t)h * 1024 + (bm >> 3) + jbl) * 64 + d) * 8) = o;
  }
}

// ---------------- K2c: strided max reduce ----------------
__global__ __launch_bounds__(256) void k_rmax(const float* __restrict__ src,
                                              float* __restrict__ dst, int n, int stride,
                                              int boff) {
  const float* p = src + (size_t)blockIdx.x * boff;
  float m = -1e30f;
  for (int k = threadIdx.x; k < n; k += 256) m = fmaxf(m, p[(size_t)k * stride]);
#pragma unroll
  for (int off = 32; off; off >>= 1) m = fmaxf(m, __shfl_xor(m, off));
  __shared__ float sm[4];
  if ((threadIdx.x & 63) == 0) sm[threadIdx.x >> 6] = m;
  __syncthreads();
  if (threadIdx.x == 0) dst[blockIdx.x] = fmaxf(fmaxf(sm[0], sm[1]), fmaxf(sm[2], sm[3]));
}

// ---------------- K2d: per-node factor tables ----------------
__global__ __launch_bounds__(256) void k_acbd(const float* __restrict__ f1i,
                                              const float* __restrict__ f2i,
                                              const float* __restrict__ f2max,
                                              float2* __restrict__ ACh,
                                              unsigned int* __restrict__ BDh) {
  const int idx = blockIdx.x * 256 + threadIdx.x;
  const int i = idx & (NN - 1);
  const int h = idx >> 13;
  const float fm = f2max[h];
  const float f1 = f1i[(size_t)i * 4 + h];
  const float f2 = f2i[(size_t)i * 4 + h];
  const float s = f1 + fm;
  const float mrow = fmaxf(s, 0.1f * s);
  float2 ac;
  ac.x = __expf(s - mrow);
  ac.y = __expf(0.1f * s - mrow);
  ACh[(size_t)h * NN + i] = ac;
  const float t = f2 - fm;
  const unsigned int B = (unsigned short)f2b(__expf(t));
  const unsigned int D = (unsigned short)f2b(__expf(0.1f * t));
  BDh[(size_t)h * NN + i] = B | (D << 16);
}

// ---------------- K3: fused adj-scan + masked dense MFMA layer-1 ----------------
// grid (512): block = 16 rows x ALL 4 heads; wave = head.
// Phase 1: adj stripe -> LDS bitmask + global bmask (single adj read, nontemporal).
// Phase 2: w'_ij = mask * max(A_i*B_j, C_i*D_j); one GEMM vs Whf; rowsum in-register.
__global__ __launch_bounds__(256) void k_dense1f(const float* __restrict__ adj,
                                                 const short* __restrict__ Whf,
                                                 const float2* __restrict__ ACh,
                                                 const unsigned int* __restrict__ BDh,
                                                 short* __restrict__ hcat,
                                                 unsigned int* __restrict__ bmask) {
  __shared__ unsigned int sm_mask[16][257];   // 16 rows x 8192 bits, stride 257 (bank-spread)
  __shared__ float sm_iv[4][16];
  __shared__ short sm_out[16][264];
  const int i0 = blockIdx.x * 16;
  const int tid = threadIdx.x;
  const int wv = tid >> 6, lane = tid & 63;
  const int mr = lane & 15, kg = lane >> 4;

  // ---- phase 1: adj -> bitmask (per-thread contiguous 512-col segment) ----
  {
    const int row = tid >> 4, seg = tid & 15;
    const fv4* a4 = reinterpret_cast<const fv4*>(adj) + (size_t)(i0 + row) * 2048 + seg * 128;
    unsigned int* brow = bmask + (size_t)(i0 + row) * 256 + seg * 16;
#pragma unroll 2
    for (int w = 0; w < 16; ++w) {
      unsigned int nv = 0;
#pragma unroll
      for (int q = 0; q < 8; ++q) {
        const fv4 v = __builtin_nontemporal_load(a4 + w * 8 + q);
        nv |= ((unsigned int)(v.x > 0.f) | ((unsigned int)(v.y > 0.f) << 1) |
               ((unsigned int)(v.z > 0.f) << 2) | ((unsigned int)(v.w > 0.f) << 3))
              << (q * 4);
      }
      sm_mask[row][seg * 16 + w] = nv;
      brow[w] = nv;
    }
  }
  __syncthreads();

  // ---- phase 2: wave = head; K-loop with zero barriers ----
  const float2 ac = ACh[(size_t)wv * NN + i0 + mr];
  f32x4 acc0 = {0.f, 0.f, 0.f, 0.f}, acc1 = acc0, acc2 = acc0, acc3 = acc0;
  float rs = 0.f;
  const unsigned int* bdh = BDh + (size_t)wv * NN;
  const short* whf = Whf + (size_t)wv * 1024 * 64 * 8 + (size_t)mr * 8;
#pragma unroll 2
  for (int ks = 0; ks < 256; ++ks) {
    const int j = ks * 32 + kg * 8;
    const unsigned int mb = (sm_mask[mr][ks] >> (kg * 8)) & 0xffu;
    const uint4 bda = *reinterpret_cast<const uint4*>(bdh + j);
    const uint4 bdb = *reinterpret_cast<const uint4*>(bdh + j + 4);
    bf16x8 af;
#define MKW(e, bdw)                                              \
    {                                                            \
      const float Bf = __uint_as_float((bdw) << 16);             \
      const float Df = __uint_as_float((bdw) & 0xffff0000u);     \
      float w_ = fmaxf(ac.x * Bf, ac.y * Df);                    \
      w_ = ((mb >> (e)) & 1u) ? w_ : 0.f;                        \
      rs += w_;                                                  \
      af[e] = f2b(w_);                                           \
    }
    MKW(0, bda.x) MKW(1, bda.y) MKW(2, bda.z) MKW(3, bda.w)
    MKW(4, bdb.x) MKW(5, bdb.y) MKW(6, bdb.z) MKW(7, bdb.w)
#undef MKW
    const short* wp = whf + (size_t)(j >> 3) * 512;   // (j/8)*64 d * 8
    const bf16x8 bf0 = *reinterpret_cast<const bf16x8*>(wp);
    const bf16x8 bf1 = *reinterpret_cast<const bf16x8*>(wp + 128);
    const bf16x8 bf2 = *reinterpret_cast<const bf16x8*>(wp + 256);
    const bf16x8 bf3 = *reinterpret_cast<const bf16x8*>(wp + 384);
    acc0 = __builtin_amdgcn_mfma_f32_16x16x32_bf16(af, bf0, acc0, 0, 0, 0);
    acc1 = __builtin_amdgcn_mfma_f32_16x16x32_bf16(af, bf1, acc1, 0, 0, 0);
    acc2 = __builtin_amdgcn_mfma_f32_16x16x32_bf16(af, bf2, acc2, 0, 0, 0);
    acc3 = __builtin_amdgcn_mfma_f32_16x16x32_bf16(af, bf3, acc3, 0, 0, 0);
  }
  rs += __shfl_xor(rs, 16);
  rs += __shfl_xor(rs, 32);
  if (lane < 16) sm_iv[wv][lane] = 1.f / rs;
#pragma unroll
  for (int q = 0; q < 4; ++q) {
    const float ivq = sm_iv[wv][kg * 4 + q];
    const int r = kg * 4 + q;
    sm_out[r][wv * 64 + mr +  0] = f2b(elu(acc0[q] * ivq));
    sm_out[r][wv * 64 + mr + 16] = f2b(elu(acc1[q] * ivq));
    sm_out[r][wv * 64 + mr + 32] = f2b(elu(acc2[q] * ivq));
    sm_out[r][wv * 64 + mr + 48] = f2b(elu(acc3[q] * ivq));
  }
  __syncthreads();
  {
    const int row = tid >> 4, sgo = (tid & 15) * 16;
    bf16x8 o0, o1;
#pragma unroll
    for (int u = 0; u < 8; ++u) {
      o0[u] = sm_out[row][sgo + u];
      o1[u] = sm_out[row][sgo + 8 + u];
    }
    short* dst = hcat + (size_t)(i0 + row) * 256 + sgo;
    *reinterpret_cast<bf16x8*>(dst) = o0;
    *reinterpret_cast<bf16x8*>(dst + 8) = o1;
  }
}

// ---------------- K4: Wh2B = (hcat @ W_out) bf16 ; f1o/f2o ----------------
__global__ __launch_bounds__(256) void k_gemm2(const short* __restrict__ hcat,
                                               const float* __restrict__ Wout,
                                               const float* __restrict__ aout,
                                               short* __restrict__ Wh2B,
                                               float* __restrict__ f1o,
                                               float* __restrict__ f2o) {
  __shared__ float sW[NHEAD * NHID][NCLASS + 1];
  __shared__ float sh[16][NHEAD * NHID + 1];
  const int tid = threadIdx.x;
  const int r = tid >> 4, c = tid & 15;
  const int row = blockIdx.x * 16 + r;
  for (int u = tid; u < 256 * 16; u += 256) sW[u >> 4][u & 15] = Wout[u];
  for (int u = tid; u < 16 * 256; u += 256)
    sh[u >> 8][u & 255] = b2f(hcat[(size_t)(blockIdx.x * 16 + (u >> 8)) * 256 + (u & 255)]);
  __syncthreads();
  float acc = 0.f;
#pragma unroll 8
  for (int f = 0; f < 256; ++f) acc += sh[r][f] * sW[f][c];
  Wh2B[(size_t)row * NCLASS + c] = f2b(acc);
  float s1 = acc * aout[c];
  float s2 = acc * aout[NCLASS + c];
#pragma unroll
  for (int off = 8; off; off >>= 1) { s1 += __shfl_xor(s1, off); s2 += __shfl_xor(s2, off); }
  if (c == 0) { f1o[row] = s1; f2o[row] = s2; }
}

// ---------------- K5: layer-2 attention from bitmask + log_softmax ----------------
__global__ __launch_bounds__(256) void k_attn2(const unsigned int* __restrict__ bmask,
                                               const short* __restrict__ Wh2B,
                                               const float* __restrict__ f1o,
                                               const float* __restrict__ f2o,
                                               const float* __restrict__ f2omax,
                                               float* __restrict__ out) {
  __shared__ unsigned short idx[CAP];
  __shared__ unsigned int wj[CAP + 4];
  __shared__ float red[4][NCLASS];
  __shared__ float swp[4];
  __shared__ float sinvs;
  __shared__ int cnt;
  const int i = blockIdx.x;
  const int tid = threadIdx.x;
  const int wv = tid >> 6, lane = tid & 63;
  if (tid == 0) cnt = 0;
  __syncthreads();

  {
    unsigned int word = bmask[(size_t)i * 256 + tid];
    const int c = __popc(word);
    if (c) {
      int base = atomicAdd(&cnt, c);
      const int j0 = tid * 32;
      while (word) {
        const int b = __ffs(word) - 1;
        word &= word - 1;
        if (base < CAP) idx[base++] = (unsigned short)(j0 + b);
      }
    }
  }
  __syncthreads();
  const int n = min(cnt, CAP);
  if (tid < 4) wj[n + tid] = 0;

  const float f1r = f1o[i];
  const float mrow = lrelu(f1r + f2omax[0]);
  float sw = 0.f;
  for (int k = tid; k < n; k += 256) {
    const int j = idx[k];
    const float w = __expf(lrelu(f1r + f2o[j]) - mrow);
    wj[k] = ((unsigned int)(unsigned short)f2b(w) << 16) | (unsigned int)j;
    sw += w;
  }
#pragma unroll
  for (int off = 32; off; off >>= 1) sw += __shfl_xor(sw, off);
  if (lane == 0) swp[wv] = sw;
  __syncthreads();
  if (tid == 0) sinvs = 1.f / (swp[0] + swp[1] + swp[2] + swp[3]);
  __syncthreads();

  const int grp = tid >> 2, gl = tid & 3;
  float acc0 = 0.f, acc1 = 0.f, acc2 = 0.f, acc3 = 0.f;
  const short* wb = Wh2B + gl * 4;
  for (int kb = grp * 4; kb < n; kb += 256) {
    const uint4 pw = *reinterpret_cast<const uint4*>(wj + kb);
    const uint2 e0 = *reinterpret_cast<const uint2*>(wb + (size_t)(pw.x & 0xffffu) * NCLASS);
    const uint2 e1 = *reinterpret_cast<const uint2*>(wb + (size_t)(pw.y & 0xffffu) * NCLASS);
    const uint2 e2 = *reinterpret_cast<const uint2*>(wb + (size_t)(pw.z & 0xffffu) * NCLASS);
    const uint2 e3 = *reinterpret_cast<const uint2*>(wb + (size_t)(pw.w & 0xffffu) * NCLASS);
    const float w0 = __uint_as_float(pw.x & 0xffff0000u);
    const float w1 = __uint_as_float(pw.y & 0xffff0000u);
    const float w2 = __uint_as_float(pw.z & 0xffff0000u);
    const float w3 = __uint_as_float(pw.w & 0xffff0000u);
    UPF(w0, e0.x, acc0, acc1) UPF(w0, e0.y, acc2, acc3)
    UPF(w1, e1.x, acc0, acc1) UPF(w1, e1.y, acc2, acc3)
    UPF(w2, e2.x, acc0, acc1) UPF(w2, e2.y, acc2, acc3)
    UPF(w3, e3.x, acc0, acc1) UPF(w3, e3.y, acc2, acc3)
  }
  acc0 += __shfl_xor(acc0, 4);  acc1 += __shfl_xor(acc1, 4);
  acc2 += __shfl_xor(acc2, 4);  acc3 += __shfl_xor(acc3, 4);
  acc0 += __shfl_xor(acc0, 8);  acc1 += __shfl_xor(acc1, 8);
  acc2 += __shfl_xor(acc2, 8);  acc3 += __shfl_xor(acc3, 8);
  acc0 += __shfl_xor(acc0, 16); acc1 += __shfl_xor(acc1, 16);
  acc2 += __shfl_xor(acc2, 16); acc3 += __shfl_xor(acc3, 16);
  acc0 += __shfl_xor(acc0, 32); acc1 += __shfl_xor(acc1, 32);
  acc2 += __shfl_xor(acc2, 32); acc3 += __shfl_xor(acc3, 32);
  if (lane < 4) {
    red[wv][lane * 4 + 0] = acc0;
    red[wv][lane * 4 + 1] = acc1;
    red[wv][lane * 4 + 2] = acc2;
    red[wv][lane * 4 + 3] = acc3;
  }
  __syncthreads();
  if (tid < NCLASS) {
    const float s = red[0][tid] + red[1][tid] + red[2][tid] + red[3][tid];
    const float v = elu(s * sinvs);
    float vm = v;
#pragma unroll
    for (int off = 8; off; off >>= 1) vm = fmaxf(vm, __shfl_xor(vm, off, 16));
    float ex = __expf(v - vm);
#pragma unroll
    for (int off = 8; off; off >>= 1) ex += __shfl_xor(ex, off, 16);
    out[(size_t)i * NCLASS + tid] = v - vm - __logf(ex);
  }
}

extern "C" void kernel_launch(void* const* d_in, const int* in_sizes, int n_in,
                              void* d_out, int out_size, void* d_ws, size_t ws_size,
                              hipStream_t stream) {
  const float* x    = (const float*)d_in[0];
  const float* adj  = (const float*)d_in[1];
  const float* W    = (const float*)d_in[2];
  const float* a    = (const float*)d_in[3];
  const float* Wout = (const float*)d_in[4];
  const float* aout = (const float*)d_in[5];
  float* out = (float*)d_out;
  char* ws = (char*)d_ws;
  const size_t MB = 1048576;
  const size_t KB = 1024;

  unsigned int* bmask  = (unsigned int*)(ws);                    //  8 MB
  short* Whf           = (short*)(ws + 8 * MB);                  //  4 MB
  short* hcat          = (short*)(ws + 12 * MB);                 //  4 MB
  short* WB            = (short*)(ws + 16 * MB);                 // 256 KB
  float* f1i           = (float*)(ws + 16 * MB + 256 * KB);      // 128 KB
  float* f2i           = (float*)(ws + 16 * MB + 384 * KB);      // 128 KB
  float2* ACh          = (float2*)(ws + 16 * MB + 512 * KB);     // 256 KB
  unsigned int* BDh    = (unsigned int*)(ws + 16 * MB + 768 * KB); // 128 KB
  float* f1o           = (float*)(ws + 16 * MB + 896 * KB);      //  32 KB
  float* f2o           = (float*)(ws + 16 * MB + 928 * KB);      //  32 KB
  short* Wh2B          = (short*)(ws + 16 * MB + 960 * KB);      // 256 KB
  float* f2max         = (float*)(ws + 16 * MB + 1216 * KB);     //  16 B
  float* f2omax        = (float*)(ws + 16 * MB + 1216 * KB + 64);

  k_wprep<<<dim3(8, 4), 256, 0, stream>>>(W, WB);
  k_prep1<<<512, 256, 0, stream>>>(x, WB, a, Whf, f1i, f2i);
  k_rmax<<<NHEAD, 256, 0, stream>>>(f2i, f2max, NN, 4, 1);
  k_acbd<<<NN * NHEAD / 256, 256, 0, stream>>>(f1i, f2i, f2max, ACh, BDh);
  k_dense1f<<<NN / 16, 256, 0, stream>>>(adj, Whf, ACh, BDh, hcat, bmask);
  k_gemm2<<<NN / 16, 256, 0, stream>>>(hcat, Wout, aout, Wh2B, f1o, f2o);
  k_rmax<<<1, 256, 0, stream>>>(f2o, f2omax, NN, 1, 0);
  k_attn2<<<NN, 256, 0, stream>>>(bmask, Wh2B, f1o, f2o, f2omax, out);
}

// Round 14
// 226.678 us; speedup vs baseline: 1.3796x; 1.3796x over previous
//
#include <hip/hip_runtime.h>
#include <hip/hip_bf16.h>

#define NN 8192
#define NFEAT 512
#define NHID 64
#define NCLASS 16
#define NHEAD 4
#define ALPHA 0.1f
#define CAP 768
#define ZSPLIT 4
#define JPB (NN / ZSPLIT)   // 2048 j per block
#define DCH 512

typedef short bf16x8 __attribute__((ext_vector_type(8)));
typedef float f32x4 __attribute__((ext_vector_type(4)));
typedef float fv4 __attribute__((ext_vector_type(4)));

__device__ __forceinline__ float lrelu(float x) { return fmaxf(x, ALPHA * x); }
__device__ __forceinline__ float elu(float x) { return x > 0.f ? x : __expf(x) - 1.f; }
__device__ __forceinline__ short f2b(float x) {
  union { __bf16 b; short s; } c; c.b = (__bf16)x; return c.s;
}
__device__ __forceinline__ float b2f(short x) {
  union { unsigned int u; float f; } c; c.u = ((unsigned int)(unsigned short)x) << 16; return c.f;
}

#define UPF(w, v, A0, A1)                                  \
  {                                                        \
    const float lo_ = __uint_as_float((v) << 16);          \
    const float hi_ = __uint_as_float((v) & 0xffff0000u);  \
    (A0) += (w) * lo_;                                     \
    (A1) += (w) * hi_;                                     \
  }

// ---------------- K0b: WB[h][d][k] = bf16(W[h][k][d]) ----------------
__global__ __launch_bounds__(256) void k_wprep(const float* __restrict__ W,
                                               short* __restrict__ WB) {
  __shared__ float t[64][65];
  const int h = blockIdx.y;
  const int k0 = blockIdx.x * 64;
  const int tid = threadIdx.x;
#pragma unroll
  for (int it = 0; it < 16; ++it) {
    const int r = it * 4 + (tid >> 6), c = tid & 63;
    t[r][c] = W[((size_t)h * NFEAT + k0 + r) * NHID + c];
  }
  __syncthreads();
#pragma unroll
  for (int it = 0; it < 16; ++it) {
    const int d = it * 4 + (tid >> 6), k = tid & 63;
    WB[((size_t)h * NHID + d) * NFEAT + k0 + k] = f2b(t[k][d]);
  }
}

// ---------------- K1: Wh = bf16(x) @ WB^T (MFMA); epilogue f1/f2 + Whf j-blocked ------
__global__ __launch_bounds__(256) void k_prep1(const float* __restrict__ x,
                                               const short* __restrict__ WB,
                                               const float* __restrict__ a,
                                               short* __restrict__ Whf,
                                               float* __restrict__ f1i,
                                               float* __restrict__ f2i) {
  __shared__ short tile[64][72];
  const int bid = blockIdx.x;
  const int h = bid >> 7;
  const int bm = (bid & 127) * 64;
  const int tid = threadIdx.x;
  const int wv = tid >> 6, lane = tid & 63;
  const int mr = lane & 15, kg = lane >> 4;
  f32x4 acc0 = {0.f, 0.f, 0.f, 0.f}, acc1 = acc0, acc2 = acc0, acc3 = acc0;
  const float* ap = x + (size_t)(bm + wv * 16 + mr) * NFEAT + kg * 8;
  const short* bp = WB + ((size_t)h * NHID + mr) * NFEAT + kg * 8;
#pragma unroll 2
  for (int k0 = 0; k0 < NFEAT; k0 += 32) {
    const float4 xa = *reinterpret_cast<const float4*>(ap);
    const float4 xb = *reinterpret_cast<const float4*>(ap + 4);
    bf16x8 af;
    af[0] = f2b(xa.x); af[1] = f2b(xa.y); af[2] = f2b(xa.z); af[3] = f2b(xa.w);
    af[4] = f2b(xb.x); af[5] = f2b(xb.y); af[6] = f2b(xb.z); af[7] = f2b(xb.w);
    const bf16x8 b0 = *reinterpret_cast<const bf16x8*>(bp);
    const bf16x8 b1 = *reinterpret_cast<const bf16x8*>(bp + 16 * NFEAT);
    const bf16x8 b2 = *reinterpret_cast<const bf16x8*>(bp + 32 * NFEAT);
    const bf16x8 b3 = *reinterpret_cast<const bf16x8*>(bp + 48 * NFEAT);
    acc0 = __builtin_amdgcn_mfma_f32_16x16x32_bf16(af, b0, acc0, 0, 0, 0);
    acc1 = __builtin_amdgcn_mfma_f32_16x16x32_bf16(af, b1, acc1, 0, 0, 0);
    acc2 = __builtin_amdgcn_mfma_f32_16x16x32_bf16(af, b2, acc2, 0, 0, 0);
    acc3 = __builtin_amdgcn_mfma_f32_16x16x32_bf16(af, b3, acc3, 0, 0, 0);
    ap += 32; bp += 32;
  }
  float a1v[4], a2v[4];
#pragma unroll
  for (int c = 0; c < 4; ++c) {
    a1v[c] = a[h * 128 + mr + c * 16];
    a2v[c] = a[h * 128 + 64 + mr + c * 16];
  }
#pragma unroll
  for (int q = 0; q < 4; ++q) {
    float s1 = acc0[q] * a1v[0] + acc1[q] * a1v[1] + acc2[q] * a1v[2] + acc3[q] * a1v[3];
    float s2 = acc0[q] * a2v[0] + acc1[q] * a2v[1] + acc2[q] * a2v[2] + acc3[q] * a2v[3];
#pragma unroll
    for (int off = 1; off < 16; off <<= 1) {
      s1 += __shfl_xor(s1, off);
      s2 += __shfl_xor(s2, off);
    }
    if (mr == 0) {
      const int i = bm + wv * 16 + kg * 4 + q;
      f1i[(size_t)i * 4 + h] = s1;
      f2i[(size_t)i * 4 + h] = s2;
    }
  }
#pragma unroll
  for (int q = 0; q < 4; ++q) {
    const int r = wv * 16 + kg * 4 + q;
    tile[r][mr +  0] = f2b(acc0[q]);
    tile[r][mr + 16] = f2b(acc1[q]);
    tile[r][mr + 32] = f2b(acc2[q]);
    tile[r][mr + 48] = f2b(acc3[q]);
  }
  __syncthreads();
#pragma unroll
  for (int it = 0; it < 2; ++it) {
    const int jbl = (tid >> 6) + it * 4;
    const int d = tid & 63;
    bf16x8 o;
#pragma unroll
    for (int jo = 0; jo < 8; ++jo) o[jo] = tile[jbl * 8 + jo][d];
    *reinterpret_cast<bf16x8*>(Whf +
        (((size_t)h * 1024 + (bm >> 3) + jbl) * 64 + d) * 8) = o;
  }
}

// ---------------- K2c: strided max reduce ----------------
__global__ __launch_bounds__(256) void k_rmax(const float* __restrict__ src,
                                              float* __restrict__ dst, int n, int stride,
                                              int boff) {
  const float* p = src + (size_t)blockIdx.x * boff;
  float m = -1e30f;
  for (int k = threadIdx.x; k < n; k += 256) m = fmaxf(m, p[(size_t)k * stride]);
#pragma unroll
  for (int off = 32; off; off >>= 1) m = fmaxf(m, __shfl_xor(m, off));
  __shared__ float sm[4];
  if ((threadIdx.x & 63) == 0) sm[threadIdx.x >> 6] = m;
  __syncthreads();
  if (threadIdx.x == 0) dst[blockIdx.x] = fmaxf(fmaxf(sm[0], sm[1]), fmaxf(sm[2], sm[3]));
}

// ---------------- K2d: per-node factor tables ----------------
__global__ __launch_bounds__(256) void k_acbd(const float* __restrict__ f1i,
                                              const float* __restrict__ f2i,
                                              const float* __restrict__ f2max,
                                              float2* __restrict__ ACh,
                                              unsigned int* __restrict__ BDh) {
  const int idx = blockIdx.x * 256 + threadIdx.x;
  const int i = idx & (NN - 1);
  const int h = idx >> 13;
  const float fm = f2max[h];
  const float f1 = f1i[(size_t)i * 4 + h];
  const float f2 = f2i[(size_t)i * 4 + h];
  const float s = f1 + fm;
  const float mrow = fmaxf(s, 0.1f * s);
  float2 ac;
  ac.x = __expf(s - mrow);
  ac.y = __expf(0.1f * s - mrow);
  ACh[(size_t)h * NN + i] = ac;
  const float t = f2 - fm;
  const unsigned int B = (unsigned short)f2b(__expf(t));
  const unsigned int D = (unsigned short)f2b(__expf(0.1f * t));
  BDh[(size_t)h * NN + i] = B | (D << 16);
}

// ---------------- K3a: stream adj -> bitmask (pure HBM, nontemporal) ----------------
__global__ __launch_bounds__(256) void k_scan(const float* __restrict__ adj,
                                              unsigned int* __restrict__ bmask) {
  const fv4* a4 = reinterpret_cast<const fv4*>(adj);
  const int t0 = blockIdx.x * 256 + threadIdx.x;
#pragma unroll 4
  for (int it = 0; it < 32; ++it) {
    const int g = it * 524288 + t0;
    const fv4 v = __builtin_nontemporal_load(a4 + g);
    unsigned int nv = (unsigned int)((v.x > 0.f) | ((v.y > 0.f) << 1) |
                                     ((v.z > 0.f) << 2) | ((v.w > 0.f) << 3))
                      << ((threadIdx.x & 7) * 4);
    nv |= __shfl_xor(nv, 1);
    nv |= __shfl_xor(nv, 2);
    nv |= __shfl_xor(nv, 4);
    if ((threadIdx.x & 7) == 0) bmask[g >> 3] = nv;
  }
}

// ---------------- K3b: masked dense MFMA layer-1, K-split (z = j-quarter) ----------------
// grid (128, NHEAD, ZSPLIT): block = 64 rows x 1 head x 2048 j. Inner loop = r12 verified.
// Writes f32 partial acc + partial rowsum; k_comb1 finishes.
__global__ __launch_bounds__(256) void k_dense1z(const unsigned int* __restrict__ bmask,
                                                 const short* __restrict__ Whf,
                                                 const float2* __restrict__ ACh,
                                                 const unsigned int* __restrict__ BDh,
                                                 float* __restrict__ OpP,
                                                 float* __restrict__ rsP) {
  __shared__ unsigned int sm_mask[64][16];
  __shared__ unsigned int sm_bd[DCH];
  const int i0 = blockIdx.x * 64;
  const int h = blockIdx.y;
  const int z = blockIdx.z;
  const int jb0 = z * JPB;
  const int tid = threadIdx.x;
  const int wv = tid >> 6, lane = tid & 63;
  const int mr = lane & 15, kg = lane >> 4;
  const int row_local = wv * 16 + mr;
  const float2 ac = ACh[(size_t)h * NN + i0 + row_local];
  f32x4 acc0 = {0.f, 0.f, 0.f, 0.f}, acc1 = acc0, acc2 = acc0, acc3 = acc0;
  float rs = 0.f;
  const int rr = tid >> 2, w0 = (tid & 3) * 4;

  for (int jc = jb0; jc < jb0 + JPB; jc += DCH) {
    __syncthreads();
    {
      const unsigned int* src = bmask + (size_t)(i0 + rr) * 256 + (jc >> 5);
#pragma unroll
      for (int u = 0; u < 4; ++u) sm_mask[rr][w0 + u] = src[w0 + u];
      sm_bd[tid] = BDh[(size_t)h * NN + jc + tid];
      sm_bd[tid + 256] = BDh[(size_t)h * NN + jc + tid + 256];
    }
    __syncthreads();
#pragma unroll 4
    for (int ks = 0; ks < DCH / 32; ++ks) {
      const int jl = ks * 32 + kg * 8;
      const uint4 bda = *reinterpret_cast<const uint4*>(&sm_bd[jl]);
      const uint4 bdb = *reinterpret_cast<const uint4*>(&sm_bd[jl + 4]);
      const unsigned int mb = (sm_mask[row_local][ks] >> (kg * 8)) & 0xffu;
      bf16x8 af;
#define MKW(e, bdw)                                              \
      {                                                          \
        const float Bf = __uint_as_float((bdw) << 16);           \
        const float Df = __uint_as_float((bdw) & 0xffff0000u);   \
        float w_ = fmaxf(ac.x * Bf, ac.y * Df);                  \
        w_ = ((mb >> (e)) & 1u) ? w_ : 0.f;                      \
        rs += w_;                                                \
        af[e] = f2b(w_);                                         \
      }
      MKW(0, bda.x) MKW(1, bda.y) MKW(2, bda.z) MKW(3, bda.w)
      MKW(4, bdb.x) MKW(5, bdb.y) MKW(6, bdb.z) MKW(7, bdb.w)
#undef MKW
      const short* wp = Whf + (((size_t)h * 1024 + ((jc + jl) >> 3)) * 64 + mr) * 8;
      const bf16x8 bf0 = *reinterpret_cast<const bf16x8*>(wp);
      const bf16x8 bf1 = *reinterpret_cast<const bf16x8*>(wp + 128);
      const bf16x8 bf2 = *reinterpret_cast<const bf16x8*>(wp + 256);
      const bf16x8 bf3 = *reinterpret_cast<const bf16x8*>(wp + 384);
      acc0 = __builtin_amdgcn_mfma_f32_16x16x32_bf16(af, bf0, acc0, 0, 0, 0);
      acc1 = __builtin_amdgcn_mfma_f32_16x16x32_bf16(af, bf1, acc1, 0, 0, 0);
      acc2 = __builtin_amdgcn_mfma_f32_16x16x32_bf16(af, bf2, acc2, 0, 0, 0);
      acc3 = __builtin_amdgcn_mfma_f32_16x16x32_bf16(af, bf3, acc3, 0, 0, 0);
    }
  }
  // partial rowsum: reduce over kg -> lane<16 holds row mr of this wave's 16-row tile
  rs += __shfl_xor(rs, 16);
  rs += __shfl_xor(rs, 32);
  if (lane < 16)
    rsP[((size_t)z * NHEAD + h) * NN + i0 + wv * 16 + lane] = rs;
  // partial acc: direct f32 writes (4 x 64B runs per instruction)
  float* op = OpP + (((size_t)z * NHEAD + h) * NN + i0) * 64;
#pragma unroll
  for (int q = 0; q < 4; ++q) {
    const int r = wv * 16 + kg * 4 + q;
    op[(size_t)r * 64 + mr +  0] = acc0[q];
    op[(size_t)r * 64 + mr + 16] = acc1[q];
    op[(size_t)r * 64 + mr + 32] = acc2[q];
    op[(size_t)r * 64 + mr + 48] = acc3[q];
  }
}

// ---------------- K3c: combine z-partials -> hcat bf16 ----------------
__global__ __launch_bounds__(256) void k_comb1(const float* __restrict__ OpP,
                                               const float* __restrict__ rsP,
                                               short* __restrict__ hcat) {
  const int idx = blockIdx.x * 256 + threadIdx.x;
  const int i = idx >> 8;
  const int hc = idx & 255;
  const int h = hc >> 6, d = hc & 63;
  float s = 0.f, rsum = 0.f;
#pragma unroll
  for (int z = 0; z < ZSPLIT; ++z) {
    s += OpP[(((size_t)z * NHEAD + h) * NN + i) * 64 + d];
    rsum += rsP[((size_t)z * NHEAD + h) * NN + i];
  }
  hcat[idx] = f2b(elu(s / rsum));
}

// ---------------- K4: Wh2B = (hcat @ W_out) bf16 ; f1o/f2o ----------------
__global__ __launch_bounds__(256) void k_gemm2(const short* __restrict__ hcat,
                                               const float* __restrict__ Wout,
                                               const float* __restrict__ aout,
                                               short* __restrict__ Wh2B,
                                               float* __restrict__ f1o,
                                               float* __restrict__ f2o) {
  __shared__ float sW[NHEAD * NHID][NCLASS + 1];
  __shared__ float sh[16][NHEAD * NHID + 1];
  const int tid = threadIdx.x;
  const int r = tid >> 4, c = tid & 15;
  const int row = blockIdx.x * 16 + r;
  for (int u = tid; u < 256 * 16; u += 256) sW[u >> 4][u & 15] = Wout[u];
  for (int u = tid; u < 16 * 256; u += 256)
    sh[u >> 8][u & 255] = b2f(hcat[(size_t)(blockIdx.x * 16 + (u >> 8)) * 256 + (u & 255)]);
  __syncthreads();
  float acc = 0.f;
#pragma unroll 8
  for (int f = 0; f < 256; ++f) acc += sh[r][f] * sW[f][c];
  Wh2B[(size_t)row * NCLASS + c] = f2b(acc);
  float s1 = acc * aout[c];
  float s2 = acc * aout[NCLASS + c];
#pragma unroll
  for (int off = 8; off; off >>= 1) { s1 += __shfl_xor(s1, off); s2 += __shfl_xor(s2, off); }
  if (c == 0) { f1o[row] = s1; f2o[row] = s2; }
}

// ---------------- K5: layer-2 attention from bitmask + log_softmax ----------------
__global__ __launch_bounds__(256) void k_attn2(const unsigned int* __restrict__ bmask,
                                               const short* __restrict__ Wh2B,
                                               const float* __restrict__ f1o,
                                               const float* __restrict__ f2o,
                                               const float* __restrict__ f2omax,
                                               float* __restrict__ out) {
  __shared__ unsigned short idx[CAP];
  __shared__ unsigned int wj[CAP + 4];
  __shared__ float red[4][NCLASS];
  __shared__ float swp[4];
  __shared__ float sinvs;
  __shared__ int cnt;
  const int i = blockIdx.x;
  const int tid = threadIdx.x;
  const int wv = tid >> 6, lane = tid & 63;
  if (tid == 0) cnt = 0;
  __syncthreads();

  {
    unsigned int word = bmask[(size_t)i * 256 + tid];
    const int c = __popc(word);
    if (c) {
      int base = atomicAdd(&cnt, c);
      const int j0 = tid * 32;
      while (word) {
        const int b = __ffs(word) - 1;
        word &= word - 1;
        if (base < CAP) idx[base++] = (unsigned short)(j0 + b);
      }
    }
  }
  __syncthreads();
  const int n = min(cnt, CAP);
  if (tid < 4) wj[n + tid] = 0;

  const float f1r = f1o[i];
  const float mrow = lrelu(f1r + f2omax[0]);
  float sw = 0.f;
  for (int k = tid; k < n; k += 256) {
    const int j = idx[k];
    const float w = __expf(lrelu(f1r + f2o[j]) - mrow);
    wj[k] = ((unsigned int)(unsigned short)f2b(w) << 16) | (unsigned int)j;
    sw += w;
  }
#pragma unroll
  for (int off = 32; off; off >>= 1) sw += __shfl_xor(sw, off);
  if (lane == 0) swp[wv] = sw;
  __syncthreads();
  if (tid == 0) sinvs = 1.f / (swp[0] + swp[1] + swp[2] + swp[3]);
  __syncthreads();

  const int grp = tid >> 2, gl = tid & 3;
  float acc0 = 0.f, acc1 = 0.f, acc2 = 0.f, acc3 = 0.f;
  const short* wb = Wh2B + gl * 4;
  for (int kb = grp * 4; kb < n; kb += 256) {
    const uint4 pw = *reinterpret_cast<const uint4*>(wj + kb);
    const uint2 e0 = *reinterpret_cast<const uint2*>(wb + (size_t)(pw.x & 0xffffu) * NCLASS);
    const uint2 e1 = *reinterpret_cast<const uint2*>(wb + (size_t)(pw.y & 0xffffu) * NCLASS);
    const uint2 e2 = *reinterpret_cast<const uint2*>(wb + (size_t)(pw.z & 0xffffu) * NCLASS);
    const uint2 e3 = *reinterpret_cast<const uint2*>(wb + (size_t)(pw.w & 0xffffu) * NCLASS);
    const float w0 = __uint_as_float(pw.x & 0xffff0000u);
    const float w1 = __uint_as_float(pw.y & 0xffff0000u);
    const float w2 = __uint_as_float(pw.z & 0xffff0000u);
    const float w3 = __uint_as_float(pw.w & 0xffff0000u);
    UPF(w0, e0.x, acc0, acc1) UPF(w0, e0.y, acc2, acc3)
    UPF(w1, e1.x, acc0, acc1) UPF(w1, e1.y, acc2, acc3)
    UPF(w2, e2.x, acc0, acc1) UPF(w2, e2.y, acc2, acc3)
    UPF(w3, e3.x, acc0, acc1) UPF(w3, e3.y, acc2, acc3)
  }
  acc0 += __shfl_xor(acc0, 4);  acc1 += __shfl_xor(acc1, 4);
  acc2 += __shfl_xor(acc2, 4);  acc3 += __shfl_xor(acc3, 4);
  acc0 += __shfl_xor(acc0, 8);  acc1 += __shfl_xor(acc1, 8);
  acc2 += __shfl_xor(acc2, 8);  acc3 += __shfl_xor(acc3, 8);
  acc0 += __shfl_xor(acc0, 16); acc1 += __shfl_xor(acc1, 16);
  acc2 += __shfl_xor(acc2, 16); acc3 += __shfl_xor(acc3, 16);
  acc0 += __shfl_xor(acc0, 32); acc1 += __shfl_xor(acc1, 32);
  acc2 += __shfl_xor(acc2, 32); acc3 += __shfl_xor(acc3, 32);
  if (lane < 4) {
    red[wv][lane * 4 + 0] = acc0;
    red[wv][lane * 4 + 1] = acc1;
    red[wv][lane * 4 + 2] = acc2;
    red[wv][lane * 4 + 3] = acc3;
  }
  __syncthreads();
  if (tid < NCLASS) {
    const float s = red[0][tid] + red[1][tid] + red[2][tid] + red[3][tid];
    const float v = elu(s * sinvs);
    float vm = v;
#pragma unroll
    for (int off = 8; off; off >>= 1) vm = fmaxf(vm, __shfl_xor(vm, off, 16));
    float ex = __expf(v - vm);
#pragma unroll
    for (int off = 8; off; off >>= 1) ex += __shfl_xor(ex, off, 16);
    out[(size_t)i * NCLASS + tid] = v - vm - __logf(ex);
  }
}

extern "C" void kernel_launch(void* const* d_in, const int* in_sizes, int n_in,
                              void* d_out, int out_size, void* d_ws, size_t ws_size,
                              hipStream_t stream) {
  const float* x    = (const float*)d_in[0];
  const float* adj  = (const float*)d_in[1];
  const float* W    = (const float*)d_in[2];
  const float* a    = (const float*)d_in[3];
  const float* Wout = (const float*)d_in[4];
  const float* aout = (const float*)d_in[5];
  float* out = (float*)d_out;
  char* ws = (char*)d_ws;
  const size_t MB = 1048576;
  const size_t KB = 1024;

  unsigned int* bmask  = (unsigned int*)(ws);                    //  8 MB
  short* Whf           = (short*)(ws + 8 * MB);                  //  4 MB
  short* hcat          = (short*)(ws + 12 * MB);                 //  4 MB
  float* OpP           = (float*)(ws + 16 * MB);                 // 32 MB (4z x 4h x 8192 x 64 f32)
  float* rsP           = (float*)(ws + 48 * MB);                 // 512 KB
  short* WB            = (short*)(ws + 49 * MB);                 // 256 KB
  float* f1i           = (float*)(ws + 49 * MB + 256 * KB);      // 128 KB
  float* f2i           = (float*)(ws + 49 * MB + 384 * KB);      // 128 KB
  float2* ACh          = (float2*)(ws + 49 * MB + 512 * KB);     // 256 KB
  unsigned int* BDh    = (unsigned int*)(ws + 49 * MB + 768 * KB); // 128 KB
  float* f1o           = (float*)(ws + 49 * MB + 896 * KB);      //  32 KB
  float* f2o           = (float*)(ws + 49 * MB + 928 * KB);      //  32 KB
  short* Wh2B          = (short*)(ws + 49 * MB + 960 * KB);      // 256 KB
  float* f2max         = (float*)(ws + 49 * MB + 1216 * KB);     //  16 B
  float* f2omax        = (float*)(ws + 49 * MB + 1216 * KB + 64);

  k_wprep<<<dim3(8, 4), 256, 0, stream>>>(W, WB);
  k_prep1<<<512, 256, 0, stream>>>(x, WB, a, Whf, f1i, f2i);
  k_rmax<<<NHEAD, 256, 0, stream>>>(f2i, f2max, NN, 4, 1);
  k_acbd<<<NN * NHEAD / 256, 256, 0, stream>>>(f1i, f2i, f2max, ACh, BDh);
  k_scan<<<2048, 256, 0, stream>>>(adj, bmask);
  k_dense1z<<<dim3(NN / 64, NHEAD, ZSPLIT), 256, 0, stream>>>(bmask, Whf, ACh, BDh, OpP, rsP);
  k_comb1<<<NN, 256, 0, stream>>>(OpP, rsP, hcat);
  k_gemm2<<<NN / 16, 256, 0, stream>>>(hcat, Wout, aout, Wh2B, f1o, f2o);
  k_rmax<<<1, 256, 0, stream>>>(f2o, f2omax, NN, 1, 0);
  k_attn2<<<NN, 256, 0, stream>>>(bmask, Wh2B, f1o, f2o, f2omax, out);
}

// Round 15
// 216.197 us; speedup vs baseline: 1.4465x; 1.0485x over previous
//
#include <hip/hip_runtime.h>
#include <hip/hip_bf16.h>

#define NN 8192
#define NFEAT 512
#define NHID 64
#define NCLASS 16
#define NHEAD 4
#define ALPHA 0.1f
#define CAP 768
#define ZSPLIT 4
#define JPB (NN / ZSPLIT)   // 2048 j per block
#define DCH 128             // j per staged chunk (16 KB B-tile in LDS)

typedef short bf16x8 __attribute__((ext_vector_type(8)));
typedef float f32x4 __attribute__((ext_vector_type(4)));
typedef float fv4 __attribute__((ext_vector_type(4)));

__device__ __forceinline__ float lrelu(float x) { return fmaxf(x, ALPHA * x); }
__device__ __forceinline__ float elu(float x) { return x > 0.f ? x : __expf(x) - 1.f; }
__device__ __forceinline__ short f2b(float x) {
  union { __bf16 b; short s; } c; c.b = (__bf16)x; return c.s;
}
__device__ __forceinline__ float b2f(short x) {
  union { unsigned int u; float f; } c; c.u = ((unsigned int)(unsigned short)x) << 16; return c.f;
}

#define UPF(w, v, A0, A1)                                  \
  {                                                        \
    const float lo_ = __uint_as_float((v) << 16);          \
    const float hi_ = __uint_as_float((v) & 0xffff0000u);  \
    (A0) += (w) * lo_;                                     \
    (A1) += (w) * hi_;                                     \
  }

// ---------------- K0b: WB[h][d][k] = bf16(W[h][k][d]) ----------------
__global__ __launch_bounds__(256) void k_wprep(const float* __restrict__ W,
                                               short* __restrict__ WB) {
  __shared__ float t[64][65];
  const int h = blockIdx.y;
  const int k0 = blockIdx.x * 64;
  const int tid = threadIdx.x;
#pragma unroll
  for (int it = 0; it < 16; ++it) {
    const int r = it * 4 + (tid >> 6), c = tid & 63;
    t[r][c] = W[((size_t)h * NFEAT + k0 + r) * NHID + c];
  }
  __syncthreads();
#pragma unroll
  for (int it = 0; it < 16; ++it) {
    const int d = it * 4 + (tid >> 6), k = tid & 63;
    WB[((size_t)h * NHID + d) * NFEAT + k0 + k] = f2b(t[k][d]);
  }
}

// ---------------- K1: Wh = bf16(x) @ WB^T (MFMA); epilogue f1/f2 + Whf j-blocked ------
__global__ __launch_bounds__(256) void k_prep1(const float* __restrict__ x,
                                               const short* __restrict__ WB,
                                               const float* __restrict__ a,
                                               short* __restrict__ Whf,
                                               float* __restrict__ f1i,
                                               float* __restrict__ f2i) {
  __shared__ short tile[64][72];
  const int bid = blockIdx.x;
  const int h = bid >> 7;
  const int bm = (bid & 127) * 64;
  const int tid = threadIdx.x;
  const int wv = tid >> 6, lane = tid & 63;
  const int mr = lane & 15, kg = lane >> 4;
  f32x4 acc0 = {0.f, 0.f, 0.f, 0.f}, acc1 = acc0, acc2 = acc0, acc3 = acc0;
  const float* ap = x + (size_t)(bm + wv * 16 + mr) * NFEAT + kg * 8;
  const short* bp = WB + ((size_t)h * NHID + mr) * NFEAT + kg * 8;
#pragma unroll 2
  for (int k0 = 0; k0 < NFEAT; k0 += 32) {
    const float4 xa = *reinterpret_cast<const float4*>(ap);
    const float4 xb = *reinterpret_cast<const float4*>(ap + 4);
    bf16x8 af;
    af[0] = f2b(xa.x); af[1] = f2b(xa.y); af[2] = f2b(xa.z); af[3] = f2b(xa.w);
    af[4] = f2b(xb.x); af[5] = f2b(xb.y); af[6] = f2b(xb.z); af[7] = f2b(xb.w);
    const bf16x8 b0 = *reinterpret_cast<const bf16x8*>(bp);
    const bf16x8 b1 = *reinterpret_cast<const bf16x8*>(bp + 16 * NFEAT);
    const bf16x8 b2 = *reinterpret_cast<const bf16x8*>(bp + 32 * NFEAT);
    const bf16x8 b3 = *reinterpret_cast<const bf16x8*>(bp + 48 * NFEAT);
    acc0 = __builtin_amdgcn_mfma_f32_16x16x32_bf16(af, b0, acc0, 0, 0, 0);
    acc1 = __builtin_amdgcn_mfma_f32_16x16x32_bf16(af, b1, acc1, 0, 0, 0);
    acc2 = __builtin_amdgcn_mfma_f32_16x16x32_bf16(af, b2, acc2, 0, 0, 0);
    acc3 = __builtin_amdgcn_mfma_f32_16x16x32_bf16(af, b3, acc3, 0, 0, 0);
    ap += 32; bp += 32;
  }
  float a1v[4], a2v[4];
#pragma unroll
  for (int c = 0; c < 4; ++c) {
    a1v[c] = a[h * 128 + mr + c * 16];
    a2v[c] = a[h * 128 + 64 + mr + c * 16];
  }
#pragma unroll
  for (int q = 0; q < 4; ++q) {
    float s1 = acc0[q] * a1v[0] + acc1[q] * a1v[1] + acc2[q] * a1v[2] + acc3[q] * a1v[3];
    float s2 = acc0[q] * a2v[0] + acc1[q] * a2v[1] + acc2[q] * a2v[2] + acc3[q] * a2v[3];
#pragma unroll
    for (int off = 1; off < 16; off <<= 1) {
      s1 += __shfl_xor(s1, off);
      s2 += __shfl_xor(s2, off);
    }
    if (mr == 0) {
      const int i = bm + wv * 16 + kg * 4 + q;
      f1i[(size_t)i * 4 + h] = s1;
      f2i[(size_t)i * 4 + h] = s2;
    }
  }
#pragma unroll
  for (int q = 0; q < 4; ++q) {
    const int r = wv * 16 + kg * 4 + q;
    tile[r][mr +  0] = f2b(acc0[q]);
    tile[r][mr + 16] = f2b(acc1[q]);
    tile[r][mr + 32] = f2b(acc2[q]);
    tile[r][mr + 48] = f2b(acc3[q]);
  }
  __syncthreads();
#pragma unroll
  for (int it = 0; it < 2; ++it) {
    const int jbl = (tid >> 6) + it * 4;
    const int d = tid & 63;
    bf16x8 o;
#pragma unroll
    for (int jo = 0; jo < 8; ++jo) o[jo] = tile[jbl * 8 + jo][d];
    *reinterpret_cast<bf16x8*>(Whf +
        (((size_t)h * 1024 + (bm >> 3) + jbl) * 64 + d) * 8) = o;
  }
}

// ---------------- K2c: strided max reduce ----------------
__global__ __launch_bounds__(256) void k_rmax(const float* __restrict__ src,
                                              float* __restrict__ dst, int n, int stride,
                                              int boff) {
  const float* p = src + (size_t)blockIdx.x * boff;
  float m = -1e30f;
  for (int k = threadIdx.x; k < n; k += 256) m = fmaxf(m, p[(size_t)k * stride]);
#pragma unroll
  for (int off = 32; off; off >>= 1) m = fmaxf(m, __shfl_xor(m, off));
  __shared__ float sm[4];
  if ((threadIdx.x & 63) == 0) sm[threadIdx.x >> 6] = m;
  __syncthreads();
  if (threadIdx.x == 0) dst[blockIdx.x] = fmaxf(fmaxf(sm[0], sm[1]), fmaxf(sm[2], sm[3]));
}

// ---------------- K2d: per-node factor tables ----------------
__global__ __launch_bounds__(256) void k_acbd(const float* __restrict__ f1i,
                                              const float* __restrict__ f2i,
                                              const float* __restrict__ f2max,
                                              float2* __restrict__ ACh,
                                              unsigned int* __restrict__ BDh) {
  const int idx = blockIdx.x * 256 + threadIdx.x;
  const int i = idx & (NN - 1);
  const int h = idx >> 13;
  const float fm = f2max[h];
  const float f1 = f1i[(size_t)i * 4 + h];
  const float f2 = f2i[(size_t)i * 4 + h];
  const float s = f1 + fm;
  const float mrow = fmaxf(s, 0.1f * s);
  float2 ac;
  ac.x = __expf(s - mrow);
  ac.y = __expf(0.1f * s - mrow);
  ACh[(size_t)h * NN + i] = ac;
  const float t = f2 - fm;
  const unsigned int B = (unsigned short)f2b(__expf(t));
  const unsigned int D = (unsigned short)f2b(__expf(0.1f * t));
  BDh[(size_t)h * NN + i] = B | (D << 16);
}

// ---------------- K3a: stream adj -> bitmask (pure HBM, nontemporal) ----------------
__global__ __launch_bounds__(256) void k_scan(const float* __restrict__ adj,
                                              unsigned int* __restrict__ bmask) {
  const fv4* a4 = reinterpret_cast<const fv4*>(adj);
  const int t0 = blockIdx.x * 256 + threadIdx.x;
#pragma unroll 4
  for (int it = 0; it < 32; ++it) {
    const int g = it * 524288 + t0;
    const fv4 v = __builtin_nontemporal_load(a4 + g);
    unsigned int nv = (unsigned int)((v.x > 0.f) | ((v.y > 0.f) << 1) |
                                     ((v.z > 0.f) << 2) | ((v.w > 0.f) << 3))
                      << ((threadIdx.x & 7) * 4);
    nv |= __shfl_xor(nv, 1);
    nv |= __shfl_xor(nv, 2);
    nv |= __shfl_xor(nv, 4);
    if ((threadIdx.x & 7) == 0) bmask[g >> 3] = nv;
  }
}

// ---------------- K3b: masked dense MFMA layer-1, K-split + LDS B-staging ----------------
// grid (128, NHEAD, ZSPLIT). Per 128-j chunk: stage B (16 KB contiguous), BD, masks in LDS;
// all 4 waves consume from LDS (4x dedup of the former per-wave L2 B-reads).
__global__ __launch_bounds__(256) void k_dense1z(const unsigned int* __restrict__ bmask,
                                                 const short* __restrict__ Whf,
                                                 const float2* __restrict__ ACh,
                                                 const unsigned int* __restrict__ BDh,
                                                 float* __restrict__ OpP,
                                                 float* __restrict__ rsP) {
  __shared__ short sm_b[16 * 64 * 8];          // 16 j-blocks x 64 d x 8 j = 16 KB
  __shared__ unsigned int sm_bd[DCH];          // 512 B
  __shared__ unsigned int sm_mask[64][5];      // 64 rows x 4 words (+pad)
  const int i0 = blockIdx.x * 64;
  const int h = blockIdx.y;
  const int z = blockIdx.z;
  const int jb0 = z * JPB;
  const int tid = threadIdx.x;
  const int wv = tid >> 6, lane = tid & 63;
  const int mr = lane & 15, kg = lane >> 4;
  const int row_local = wv * 16 + mr;
  const float2 ac = ACh[(size_t)h * NN + i0 + row_local];
  f32x4 acc0 = {0.f, 0.f, 0.f, 0.f}, acc1 = acc0, acc2 = acc0, acc3 = acc0;
  float rs = 0.f;

  for (int jc = jb0; jc < jb0 + JPB; jc += DCH) {
    __syncthreads();
    {
      // masks: 64 rows x 4 words
      sm_mask[tid >> 2][tid & 3] =
          bmask[(size_t)(i0 + (tid >> 2)) * 256 + (jc >> 5) + (tid & 3)];
      // BD factors
      if (tid < DCH) sm_bd[tid] = BDh[(size_t)h * NN + jc + tid];
      // B-tile: 16 KB contiguous in Whf's j-blocked layout
      const uint4* src = reinterpret_cast<const uint4*>(
          Whf + ((size_t)h * 1024 + (jc >> 3)) * 512);
      uint4* dst = reinterpret_cast<uint4*>(sm_b);
#pragma unroll
      for (int u = 0; u < 4; ++u) dst[tid + u * 256] = src[tid + u * 256];
    }
    __syncthreads();
#pragma unroll
    for (int ks = 0; ks < DCH / 32; ++ks) {
      const int jl = ks * 32 + kg * 8;
      const uint4 bda = *reinterpret_cast<const uint4*>(&sm_bd[jl]);
      const uint4 bdb = *reinterpret_cast<const uint4*>(&sm_bd[jl + 4]);
      const unsigned int mb = (sm_mask[row_local][ks] >> (kg * 8)) & 0xffu;
      bf16x8 af;
#define MKW(e, bdw)                                              \
      {                                                          \
        const float Bf = __uint_as_float((bdw) << 16);           \
        const float Df = __uint_as_float((bdw) & 0xffff0000u);   \
        float w_ = fmaxf(ac.x * Bf, ac.y * Df);                  \
        w_ = ((mb >> (e)) & 1u) ? w_ : 0.f;                      \
        rs += w_;                                                \
        af[e] = f2b(w_);                                         \
      }
      MKW(0, bda.x) MKW(1, bda.y) MKW(2, bda.z) MKW(3, bda.w)
      MKW(4, bdb.x) MKW(5, bdb.y) MKW(6, bdb.z) MKW(7, bdb.w)
#undef MKW
      const short* wp = sm_b + ((size_t)(jl >> 3) * 64 + mr) * 8;
      const bf16x8 bf0 = *reinterpret_cast<const bf16x8*>(wp);
      const bf16x8 bf1 = *reinterpret_cast<const bf16x8*>(wp + 128);
      const bf16x8 bf2 = *reinterpret_cast<const bf16x8*>(wp + 256);
      const bf16x8 bf3 = *reinterpret_cast<const bf16x8*>(wp + 384);
      acc0 = __builtin_amdgcn_mfma_f32_16x16x32_bf16(af, bf0, acc0, 0, 0, 0);
      acc1 = __builtin_amdgcn_mfma_f32_16x16x32_bf16(af, bf1, acc1, 0, 0, 0);
      acc2 = __builtin_amdgcn_mfma_f32_16x16x32_bf16(af, bf2, acc2, 0, 0, 0);
      acc3 = __builtin_amdgcn_mfma_f32_16x16x32_bf16(af, bf3, acc3, 0, 0, 0);
    }
  }
  rs += __shfl_xor(rs, 16);
  rs += __shfl_xor(rs, 32);
  if (lane < 16)
    rsP[((size_t)z * NHEAD + h) * NN + i0 + wv * 16 + lane] = rs;
  float* op = OpP + (((size_t)z * NHEAD + h) * NN + i0) * 64;
#pragma unroll
  for (int q = 0; q < 4; ++q) {
    const int r = wv * 16 + kg * 4 + q;
    op[(size_t)r * 64 + mr +  0] = acc0[q];
    op[(size_t)r * 64 + mr + 16] = acc1[q];
    op[(size_t)r * 64 + mr + 32] = acc2[q];
    op[(size_t)r * 64 + mr + 48] = acc3[q];
  }
}

// ---------------- K3c: combine z-partials -> hcat bf16 ----------------
__global__ __launch_bounds__(256) void k_comb1(const float* __restrict__ OpP,
                                               const float* __restrict__ rsP,
                                               short* __restrict__ hcat) {
  const int idx = blockIdx.x * 256 + threadIdx.x;
  const int i = idx >> 8;
  const int hc = idx & 255;
  const int h = hc >> 6, d = hc & 63;
  float s = 0.f, rsum = 0.f;
#pragma unroll
  for (int z = 0; z < ZSPLIT; ++z) {
    s += OpP[(((size_t)z * NHEAD + h) * NN + i) * 64 + d];
    rsum += rsP[((size_t)z * NHEAD + h) * NN + i];
  }
  hcat[idx] = f2b(elu(s / rsum));
}

// ---------------- K4: Wh2B = (hcat @ W_out) bf16 ; f1o/f2o ----------------
__global__ __launch_bounds__(256) void k_gemm2(const short* __restrict__ hcat,
                                               const float* __restrict__ Wout,
                                               const float* __restrict__ aout,
                                               short* __restrict__ Wh2B,
                                               float* __restrict__ f1o,
                                               float* __restrict__ f2o) {
  __shared__ float sW[NHEAD * NHID][NCLASS + 1];
  __shared__ float sh[16][NHEAD * NHID + 1];
  const int tid = threadIdx.x;
  const int r = tid >> 4, c = tid & 15;
  const int row = blockIdx.x * 16 + r;
  for (int u = tid; u < 256 * 16; u += 256) sW[u >> 4][u & 15] = Wout[u];
  for (int u = tid; u < 16 * 256; u += 256)
    sh[u >> 8][u & 255] = b2f(hcat[(size_t)(blockIdx.x * 16 + (u >> 8)) * 256 + (u & 255)]);
  __syncthreads();
  float acc = 0.f;
#pragma unroll 8
  for (int f = 0; f < 256; ++f) acc += sh[r][f] * sW[f][c];
  Wh2B[(size_t)row * NCLASS + c] = f2b(acc);
  float s1 = acc * aout[c];
  float s2 = acc * aout[NCLASS + c];
#pragma unroll
  for (int off = 8; off; off >>= 1) { s1 += __shfl_xor(s1, off); s2 += __shfl_xor(s2, off); }
  if (c == 0) { f1o[row] = s1; f2o[row] = s2; }
}

// ---------------- K5: layer-2 attention from bitmask + log_softmax ----------------
__global__ __launch_bounds__(256) void k_attn2(const unsigned int* __restrict__ bmask,
                                               const short* __restrict__ Wh2B,
                                               const float* __restrict__ f1o,
                                               const float* __restrict__ f2o,
                                               const float* __restrict__ f2omax,
                                               float* __restrict__ out) {
  __shared__ unsigned short idx[CAP];
  __shared__ unsigned int wj[CAP + 4];
  __shared__ float red[4][NCLASS];
  __shared__ float swp[4];
  __shared__ float sinvs;
  __shared__ int cnt;
  const int i = blockIdx.x;
  const int tid = threadIdx.x;
  const int wv = tid >> 6, lane = tid & 63;
  if (tid == 0) cnt = 0;
  __syncthreads();

  {
    unsigned int word = bmask[(size_t)i * 256 + tid];
    const int c = __popc(word);
    if (c) {
      int base = atomicAdd(&cnt, c);
      const int j0 = tid * 32;
      while (word) {
        const int b = __ffs(word) - 1;
        word &= word - 1;
        if (base < CAP) idx[base++] = (unsigned short)(j0 + b);
      }
    }
  }
  __syncthreads();
  const int n = min(cnt, CAP);
  if (tid < 4) wj[n + tid] = 0;

  const float f1r = f1o[i];
  const float mrow = lrelu(f1r + f2omax[0]);
  float sw = 0.f;
  for (int k = tid; k < n; k += 256) {
    const int j = idx[k];
    const float w = __expf(lrelu(f1r + f2o[j]) - mrow);
    wj[k] = ((unsigned int)(unsigned short)f2b(w) << 16) | (unsigned int)j;
    sw += w;
  }
#pragma unroll
  for (int off = 32; off; off >>= 1) sw += __shfl_xor(sw, off);
  if (lane == 0) swp[wv] = sw;
  __syncthreads();
  if (tid == 0) sinvs = 1.f / (swp[0] + swp[1] + swp[2] + swp[3]);
  __syncthreads();

  const int grp = tid >> 2, gl = tid & 3;
  float acc0 = 0.f, acc1 = 0.f, acc2 = 0.f, acc3 = 0.f;
  const short* wb = Wh2B + gl * 4;
  for (int kb = grp * 4; kb < n; kb += 256) {
    const uint4 pw = *reinterpret_cast<const uint4*>(wj + kb);
    const uint2 e0 = *reinterpret_cast<const uint2*>(wb + (size_t)(pw.x & 0xffffu) * NCLASS);
    const uint2 e1 = *reinterpret_cast<const uint2*>(wb + (size_t)(pw.y & 0xffffu) * NCLASS);
    const uint2 e2 = *reinterpret_cast<const uint2*>(wb + (size_t)(pw.z & 0xffffu) * NCLASS);
    const uint2 e3 = *reinterpret_cast<const uint2*>(wb + (size_t)(pw.w & 0xffffu) * NCLASS);
    const float w0 = __uint_as_float(pw.x & 0xffff0000u);
    const float w1 = __uint_as_float(pw.y & 0xffff0000u);
    const float w2 = __uint_as_float(pw.z & 0xffff0000u);
    const float w3 = __uint_as_float(pw.w & 0xffff0000u);
    UPF(w0, e0.x, acc0, acc1) UPF(w0, e0.y, acc2, acc3)
    UPF(w1, e1.x, acc0, acc1) UPF(w1, e1.y, acc2, acc3)
    UPF(w2, e2.x, acc0, acc1) UPF(w2, e2.y, acc2, acc3)
    UPF(w3, e3.x, acc0, acc1) UPF(w3, e3.y, acc2, acc3)
  }
  acc0 += __shfl_xor(acc0, 4);  acc1 += __shfl_xor(acc1, 4);
  acc2 += __shfl_xor(acc2, 4);  acc3 += __shfl_xor(acc3, 4);
  acc0 += __shfl_xor(acc0, 8);  acc1 += __shfl_xor(acc1, 8);
  acc2 += __shfl_xor(acc2, 8);  acc3 += __shfl_xor(acc3, 8);
  acc0 += __shfl_xor(acc0, 16); acc1 += __shfl_xor(acc1, 16);
  acc2 += __shfl_xor(acc2, 16); acc3 += __shfl_xor(acc3, 16);
  acc0 += __shfl_xor(acc0, 32); acc1 += __shfl_xor(acc1, 32);
  acc2 += __shfl_xor(acc2, 32); acc3 += __shfl_xor(acc3, 32);
  if (lane < 4) {
    red[wv][lane * 4 + 0] = acc0;
    red[wv][lane * 4 + 1] = acc1;
    red[wv][lane * 4 + 2] = acc2;
    red[wv][lane * 4 + 3] = acc3;
  }
  __syncthreads();
  if (tid < NCLASS) {
    const float s = red[0][tid] + red[1][tid] + red[2][tid] + red[3][tid];
    const float v = elu(s * sinvs);
    float vm = v;
#pragma unroll
    for (int off = 8; off; off >>= 1) vm = fmaxf(vm, __shfl_xor(vm, off, 16));
    float ex = __expf(v - vm);
#pragma unroll
    for (int off = 8; off; off >>= 1) ex += __shfl_xor(ex, off, 16);
    out[(size_t)i * NCLASS + tid] = v - vm - __logf(ex);
  }
}

extern "C" void kernel_launch(void* const* d_in, const int* in_sizes, int n_in,
                              void* d_out, int out_size, void* d_ws, size_t ws_size,
                              hipStream_t stream) {
  const float* x    = (const float*)d_in[0];
  const float* adj  = (const float*)d_in[1];
  const float* W    = (const float*)d_in[2];
  const float* a    = (const float*)d_in[3];
  const float* Wout = (const float*)d_in[4];
  const float* aout = (const float*)d_in[5];
  float* out = (float*)d_out;
  char* ws = (char*)d_ws;
  const size_t MB = 1048576;
  const size_t KB = 1024;

  unsigned int* bmask  = (unsigned int*)(ws);                    //  8 MB
  short* Whf           = (short*)(ws + 8 * MB);                  //  4 MB
  short* hcat          = (short*)(ws + 12 * MB);                 //  4 MB
  float* OpP           = (float*)(ws + 16 * MB);                 // 32 MB
  float* rsP           = (float*)(ws + 48 * MB);                 // 512 KB
  short* WB            = (short*)(ws + 49 * MB);                 // 256 KB
  float* f1i           = (float*)(ws + 49 * MB + 256 * KB);      // 128 KB
  float* f2i           = (float*)(ws + 49 * MB + 384 * KB);      // 128 KB
  float2* ACh          = (float2*)(ws + 49 * MB + 512 * KB);     // 256 KB
  unsigned int* BDh    = (unsigned int*)(ws + 49 * MB + 768 * KB); // 128 KB
  float* f1o           = (float*)(ws + 49 * MB + 896 * KB);      //  32 KB
  float* f2o           = (float*)(ws + 49 * MB + 928 * KB);      //  32 KB
  short* Wh2B          = (short*)(ws + 49 * MB + 960 * KB);      // 256 KB
  float* f2max         = (float*)(ws + 49 * MB + 1216 * KB);     //  16 B
  float* f2omax        = (float*)(ws + 49 * MB + 1216 * KB + 64);

  k_wprep<<<dim3(8, 4), 256, 0, stream>>>(W, WB);
  k_prep1<<<512, 256, 0, stream>>>(x, WB, a, Whf, f1i, f2i);
  k_rmax<<<NHEAD, 256, 0, stream>>>(f2i, f2max, NN, 4, 1);
  k_acbd<<<NN * NHEAD / 256, 256, 0, stream>>>(f1i, f2i, f2max, ACh, BDh);
  k_scan<<<2048, 256, 0, stream>>>(adj, bmask);
  k_dense1z<<<dim3(NN / 64, NHEAD, ZSPLIT), 256, 0, stream>>>(bmask, Whf, ACh, BDh, OpP, rsP);
  k_comb1<<<NN, 256, 0, stream>>>(OpP, rsP, hcat);
  k_gemm2<<<NN / 16, 256, 0, stream>>>(hcat, Wout, aout, Wh2B, f1o, f2o);
  k_rmax<<<1, 256, 0, stream>>>(f2o, f2omax, NN, 1, 0);
  k_attn2<<<NN, 256, 0, stream>>>(bmask, Wh2B, f1o, f2o, f2omax, out);
}